// Round 3
// baseline (30982.626 us; speedup 1.0000x reference)
//
#include <hip/hip_runtime.h>
#include <hip/hip_cooperative_groups.h>

namespace cg = cooperative_groups;

#define B_ 512
#define S_ 128
#define T_ 128
#define D_ 512
#define V_ 128
#define LDW 80

typedef __attribute__((ext_vector_type(8))) short s16x8;
typedef __attribute__((ext_vector_type(4))) short s16x4;
typedef __attribute__((ext_vector_type(4))) float f32x4;

__device__ __forceinline__ float b2f(unsigned short h) {
    union { unsigned int u; float f; } x; x.u = ((unsigned int)h) << 16; return x.f;
}
__device__ __forceinline__ unsigned short f2b(float f) {
    union { float f; unsigned int u; } x; x.f = f;
    unsigned int u = x.u; u += 0x7FFFu + ((u >> 16) & 1u);
    return (unsigned short)(u >> 16);
}
__device__ __forceinline__ float sigm(float x) { return 1.0f / (1.0f + __expf(-x)); }
__device__ __forceinline__ float tanh_fast(float x) {
    float e = __expf(-2.0f * fabsf(x));
    float r = (1.0f - e) / (1.0f + e);
    return copysignf(r, x);
}

struct P {
    const int* target;
    const float* E; const float* Va; const float* bv; const float* ba; const float* bout;
    const short* ealb; const short* kpb;
    const short* WaT; const short* WcatT; const short* WoutT;
    const float* bcat;
    float* qb; short* xcat0; short* xcat1; short* hcbf; short* h2bf; float* cst;
    float* out_logits; float* out_attn;
};

struct AttnS { float sc[S_]; float wbuf[S_]; float red[2]; float cpart[4][D_]; };
struct GateS { short As[64][LDW]; short Bs[64][LDW]; float gt[64][68]; };
struct OutS  { short As[64][LDW]; short Bs[128][LDW]; };
union SharedU { AttnS a; GateS g; OutS o; };

// ---------------- phase A: attention (block b = batch row) ----------------
__device__ __forceinline__ void attn_phase(const P& p, AttnS& sh, int b, int step, short* xc)
{
    const int t = threadIdx.x, lane = t & 63, wave = t >> 6;
    const int d0 = lane * 8;
    float qr[8], var[8];
    const float* qrow = p.qb + (size_t)b * D_ + d0;
    #pragma unroll
    for (int j = 0; j < 8; ++j) { qr[j] = qrow[j]; var[j] = p.Va[d0 + j]; }
    const float bvv = p.bv[0];
    #pragma unroll 4
    for (int i = 0; i < 32; ++i) {
        int s = wave * 32 + i;
        s16x8 kv = *(const s16x8*)(p.kpb + ((size_t)b * S_ + s) * D_ + d0);
        float acc = 0.f;
        #pragma unroll
        for (int j = 0; j < 8; ++j)
            acc += tanh_fast(qr[j] + b2f((unsigned short)kv[j])) * var[j];
        #pragma unroll
        for (int o = 32; o >= 1; o >>= 1) acc += __shfl_xor(acc, o);
        if (lane == 0) sh.sc[s] = acc + bvv;
    }
    __syncthreads();
    if (wave == 0) {
        float v0 = sh.sc[lane], v1 = sh.sc[lane + 64];
        float m = fmaxf(v0, v1);
        #pragma unroll
        for (int o = 32; o >= 1; o >>= 1) m = fmaxf(m, __shfl_xor(m, o));
        float su = __expf(v0 - m) + __expf(v1 - m);
        #pragma unroll
        for (int o = 32; o >= 1; o >>= 1) su += __shfl_xor(su, o);
        if (lane == 0) { sh.red[0] = m; sh.red[1] = su; }
    }
    __syncthreads();
    {
        float m = sh.red[0], inv = 1.0f / sh.red[1];
        if (t < S_) {
            float w = __expf(sh.sc[t] - m) * inv;
            sh.wbuf[t] = w;
            p.out_attn[((size_t)b * T_ + step) * S_ + t] = w;
        }
    }
    __syncthreads();
    {
        f32x4 aA = {0.f,0.f,0.f,0.f}, aB = {0.f,0.f,0.f,0.f};
        const short* eb = p.ealb + (size_t)b * S_ * D_ + d0;
        #pragma unroll 4
        for (int i = 0; i < 32; ++i) {
            int s = wave * 32 + i;
            float wv = sh.wbuf[s];
            s16x8 ev = *(const s16x8*)(eb + (size_t)s * D_);
            #pragma unroll
            for (int j = 0; j < 4; ++j) aA[j] += wv * b2f((unsigned short)ev[j]);
            #pragma unroll
            for (int j = 0; j < 4; ++j) aB[j] += wv * b2f((unsigned short)ev[4 + j]);
        }
        *(f32x4*)&sh.cpart[wave][d0]     = aA;
        *(f32x4*)&sh.cpart[wave][d0 + 4] = aB;
    }
    __syncthreads();
    {
        int dd = t * 2;
        float v0 = sh.cpart[0][dd]   + sh.cpart[1][dd]   + sh.cpart[2][dd]   + sh.cpart[3][dd];
        float v1 = sh.cpart[0][dd+1] + sh.cpart[1][dd+1] + sh.cpart[2][dd+1] + sh.cpart[3][dd+1];
        short2 o2; o2.x = (short)f2b(v0); o2.y = (short)f2b(v1);
        *(short2*)(xc + (size_t)b * 1536 + 512 + dd) = o2;
    }
}

// ---------------- phase B: gate GEMM 64x64 (gate-interleaved cols) + LSTM (bid < 256) ----------------
__device__ __forceinline__ void gate_phase(const P& p, GateS& sh, int bid, int step,
                                           const short* xc, short* xn)
{
    const int t = threadIdx.x, lane = t & 63, wave = t >> 6;
    const int wr = wave >> 1, wc = wave & 1;
    const int lrow = lane & 15, kq = lane >> 4;
    const int srow = t >> 3, sseg = t & 7;
    const int m0 = (bid >> 5) * 64, n0 = (bid & 31) * 64;
    const int K = 1536;
    f32x4 acc[2][2] = {};
    for (int k0 = 0; k0 < K; k0 += 64) {
        s16x8 va0 = *(const s16x8*)(xc + (size_t)(m0 + srow) * K + k0 + sseg * 8);
        s16x8 va1 = *(const s16x8*)(xc + (size_t)(m0 + srow + 32) * K + k0 + sseg * 8);
        s16x8 vb0 = *(const s16x8*)(p.WcatT + (size_t)(n0 + srow) * K + k0 + sseg * 8);
        s16x8 vb1 = *(const s16x8*)(p.WcatT + (size_t)(n0 + srow + 32) * K + k0 + sseg * 8);
        __syncthreads();
        *(s16x8*)(&sh.As[srow][sseg * 8]) = va0;
        *(s16x8*)(&sh.As[srow + 32][sseg * 8]) = va1;
        *(s16x8*)(&sh.Bs[srow][sseg * 8]) = vb0;
        *(s16x8*)(&sh.Bs[srow + 32][sseg * 8]) = vb1;
        __syncthreads();
        #pragma unroll
        for (int kk = 0; kk < 64; kk += 32) {
            s16x8 af0 = *(const s16x8*)(&sh.As[wr * 32 + lrow][kk + kq * 8]);
            s16x8 af1 = *(const s16x8*)(&sh.As[wr * 32 + 16 + lrow][kk + kq * 8]);
            s16x8 bf0 = *(const s16x8*)(&sh.Bs[wc * 32 + lrow][kk + kq * 8]);
            s16x8 bf1 = *(const s16x8*)(&sh.Bs[wc * 32 + 16 + lrow][kk + kq * 8]);
            acc[0][0] = __builtin_amdgcn_mfma_f32_16x16x32_bf16(af0, bf0, acc[0][0], 0, 0, 0);
            acc[0][1] = __builtin_amdgcn_mfma_f32_16x16x32_bf16(af0, bf1, acc[0][1], 0, 0, 0);
            acc[1][0] = __builtin_amdgcn_mfma_f32_16x16x32_bf16(af1, bf0, acc[1][0], 0, 0, 0);
            acc[1][1] = __builtin_amdgcn_mfma_f32_16x16x32_bf16(af1, bf1, acc[1][1], 0, 0, 0);
        }
    }
    #pragma unroll
    for (int m2 = 0; m2 < 2; ++m2)
        #pragma unroll
        for (int n2 = 0; n2 < 2; ++n2) {
            int cl = wc * 32 + n2 * 16 + lrow;
            float bvv = p.bcat[n0 + cl];
            #pragma unroll
            for (int j = 0; j < 4; ++j) {
                int rl = wr * 32 + m2 * 16 + kq * 4 + j;
                sh.gt[rl][cl] = acc[m2][n2][j] + bvv;
            }
        }
    __syncthreads();
    const int rl4 = t >> 4, dl = t & 15;
    #pragma unroll
    for (int pass = 0; pass < 4; ++pass) {
        int row = pass * 16 + rl4;
        int b = m0 + row;
        int d = (n0 >> 2) + dl;
        float gi = sh.gt[row][dl * 4 + 0];
        float gf = sh.gt[row][dl * 4 + 1];
        float gg = sh.gt[row][dl * 4 + 2];
        float go = sh.gt[row][dl * 4 + 3];
        float cv = p.cst[(size_t)b * D_ + d];
        float c2 = sigm(gf) * cv + sigm(gi) * tanh_fast(gg);
        float h2 = sigm(go) * tanh_fast(c2);
        p.cst[(size_t)b * D_ + d] = c2;
        p.hcbf[(size_t)b * D_ + d] = (short)f2b(h2 + c2);
        p.h2bf[(size_t)b * D_ + d] = (short)f2b(h2);
        xn[(size_t)b * 1536 + 1024 + d] = (short)f2b(h2);
        int tok = p.target[b * T_ + step];
        xn[(size_t)b * 1536 + d] = (short)f2b(p.E[(size_t)tok * D_ + d]);
    }
}

// ---------------- phase C: q GEMM 64x32 (bid<128) + out GEMM w/ log_softmax (bid 128..135) ----------
__device__ __forceinline__ void qout_phase(const P& p, OutS& sh, int bid, int step)
{
    const int t = threadIdx.x, lane = t & 63, wave = t >> 6;
    const int lrow = lane & 15, kq = lane >> 4;
    const int srow = t >> 3, sseg = t & 7;
    if (bid < 128) {
        const int m0 = (bid >> 4) * 64, n0 = (bid & 15) * 32;
        f32x4 acc0 = {}, acc1 = {};
        for (int k0 = 0; k0 < 512; k0 += 64) {
            s16x8 va0 = *(const s16x8*)(p.hcbf + (size_t)(m0 + srow) * 512 + k0 + sseg * 8);
            s16x8 va1 = *(const s16x8*)(p.hcbf + (size_t)(m0 + srow + 32) * 512 + k0 + sseg * 8);
            s16x8 vb0 = *(const s16x8*)(p.WaT + (size_t)(n0 + srow) * 512 + k0 + sseg * 8);
            __syncthreads();
            *(s16x8*)(&sh.As[srow][sseg * 8]) = va0;
            *(s16x8*)(&sh.As[srow + 32][sseg * 8]) = va1;
            *(s16x8*)(&sh.Bs[srow][sseg * 8]) = vb0;
            __syncthreads();
            #pragma unroll
            for (int kk = 0; kk < 64; kk += 32) {
                s16x8 af  = *(const s16x8*)(&sh.As[wave * 16 + lrow][kk + kq * 8]);
                s16x8 bf0 = *(const s16x8*)(&sh.Bs[lrow][kk + kq * 8]);
                s16x8 bf1 = *(const s16x8*)(&sh.Bs[16 + lrow][kk + kq * 8]);
                acc0 = __builtin_amdgcn_mfma_f32_16x16x32_bf16(af, bf0, acc0, 0, 0, 0);
                acc1 = __builtin_amdgcn_mfma_f32_16x16x32_bf16(af, bf1, acc1, 0, 0, 0);
            }
        }
        #pragma unroll
        for (int n2 = 0; n2 < 2; ++n2) {
            int col = n0 + n2 * 16 + lrow;
            float bvv = p.ba[col];
            f32x4 av = n2 ? acc1 : acc0;
            #pragma unroll
            for (int j = 0; j < 4; ++j) {
                int row = m0 + wave * 16 + kq * 4 + j;
                p.qb[(size_t)row * 512 + col] = av[j] + bvv;
            }
        }
    } else if (bid < 136) {
        const int m0 = (bid - 128) * 64;
        f32x4 acc[8] = {};
        for (int k0 = 0; k0 < 512; k0 += 64) {
            s16x8 va0 = *(const s16x8*)(p.h2bf + (size_t)(m0 + srow) * 512 + k0 + sseg * 8);
            s16x8 va1 = *(const s16x8*)(p.h2bf + (size_t)(m0 + srow + 32) * 512 + k0 + sseg * 8);
            s16x8 vb[4];
            #pragma unroll
            for (int p4 = 0; p4 < 4; ++p4)
                vb[p4] = *(const s16x8*)(p.WoutT + (size_t)(srow + p4 * 32) * 512 + k0 + sseg * 8);
            __syncthreads();
            *(s16x8*)(&sh.As[srow][sseg * 8]) = va0;
            *(s16x8*)(&sh.As[srow + 32][sseg * 8]) = va1;
            #pragma unroll
            for (int p4 = 0; p4 < 4; ++p4) *(s16x8*)(&sh.Bs[srow + p4 * 32][sseg * 8]) = vb[p4];
            __syncthreads();
            #pragma unroll
            for (int kk = 0; kk < 64; kk += 32) {
                s16x8 a = *(const s16x8*)(&sh.As[wave * 16 + lrow][kk + kq * 8]);
                #pragma unroll
                for (int f = 0; f < 8; ++f) {
                    s16x8 b = *(const s16x8*)(&sh.Bs[f * 16 + lrow][kk + kq * 8]);
                    acc[f] = __builtin_amdgcn_mfma_f32_16x16x32_bf16(a, b, acc[f], 0, 0, 0);
                }
            }
        }
        float colb[8];
        #pragma unroll
        for (int f = 0; f < 8; ++f) colb[f] = p.bout[f * 16 + lrow];
        #pragma unroll
        for (int j = 0; j < 4; ++j) {
            float v[8]; float mx = -1e30f;
            #pragma unroll
            for (int f = 0; f < 8; ++f) { v[f] = acc[f][j] + colb[f]; mx = fmaxf(mx, v[f]); }
            #pragma unroll
            for (int o = 1; o < 16; o <<= 1) mx = fmaxf(mx, __shfl_xor(mx, o));
            float sum = 0.f;
            #pragma unroll
            for (int f = 0; f < 8; ++f) sum += __expf(v[f] - mx);
            #pragma unroll
            for (int o = 1; o < 16; o <<= 1) sum += __shfl_xor(sum, o);
            float lse = mx + __logf(sum);
            int row = m0 + wave * 16 + kq * 4 + j;
            float* orow = p.out_logits + ((size_t)row * T_ + step) * V_;
            #pragma unroll
            for (int f = 0; f < 8; ++f) orow[f * 16 + lrow] = v[f] - lse;
        }
    }
}

// ---------------- persistent cooperative kernel: whole T loop ----------------
__global__ __launch_bounds__(256, 2)
void decode_all(P p)
{
    cg::grid_group grid = cg::this_grid();
    __shared__ SharedU sh;
    const int bid = blockIdx.x;
    for (int step = 0; step < T_; ++step) {
        short* xc = (step & 1) ? p.xcat1 : p.xcat0;
        short* xn = (step & 1) ? p.xcat0 : p.xcat1;
        attn_phase(p, sh.a, bid, step, xc);
        grid.sync();
        if (bid < 256) gate_phase(p, sh.g, bid, step, xc, xn);
        grid.sync();
        qout_phase(p, sh.o, bid, step);
        grid.sync();
    }
}

// ---------------- fallback per-step kernels (if cooperative launch unavailable) ----------------
__global__ __launch_bounds__(256, 2) void attn_k(P p, int step) {
    __shared__ SharedU sh;
    short* xc = (step & 1) ? p.xcat1 : p.xcat0;
    attn_phase(p, sh.a, blockIdx.x, step, xc);
}
__global__ __launch_bounds__(256, 2) void gate_k(P p, int step) {
    __shared__ SharedU sh;
    const short* xc = (step & 1) ? p.xcat1 : p.xcat0;
    short* xn = (step & 1) ? p.xcat0 : p.xcat1;
    gate_phase(p, sh.g, blockIdx.x, step, xc, xn);
}
__global__ __launch_bounds__(256, 2) void qout_k(P p, int step) {
    __shared__ SharedU sh;
    qout_phase(p, sh.o, blockIdx.x, step);
}

// ---------------- precompute kernels ----------------
template<bool OUT_BF16>
__global__ __launch_bounds__(256)
void gemm64(const short* __restrict__ A, const short* __restrict__ Bt,
            const float* __restrict__ bias, void* __restrict__ Cp,
            int M, int N, int K)
{
    __shared__ __align__(16) short As[64][72];
    __shared__ __align__(16) short Bs[64][72];
    const int t = threadIdx.x;
    const int lane = t & 63, wave = t >> 6;
    const int wr = wave >> 1, wc = wave & 1;
    const int lrow = lane & 15, kq = lane >> 4;
    const int m0 = blockIdx.y * 64, n0 = blockIdx.x * 64;
    const int srow = t >> 3, sseg = t & 7;
    f32x4 acc[2][2] = {};
    for (int k0 = 0; k0 < K; k0 += 64) {
        s16x8 va0 = *(const s16x8*)(A + (size_t)(m0 + srow) * K + k0 + sseg * 8);
        s16x8 va1 = *(const s16x8*)(A + (size_t)(m0 + srow + 32) * K + k0 + sseg * 8);
        s16x8 vb0 = *(const s16x8*)(Bt + (size_t)(n0 + srow) * K + k0 + sseg * 8);
        s16x8 vb1 = *(const s16x8*)(Bt + (size_t)(n0 + srow + 32) * K + k0 + sseg * 8);
        __syncthreads();
        *(s16x8*)(&As[srow][sseg * 8]) = va0;
        *(s16x8*)(&As[srow + 32][sseg * 8]) = va1;
        *(s16x8*)(&Bs[srow][sseg * 8]) = vb0;
        *(s16x8*)(&Bs[srow + 32][sseg * 8]) = vb1;
        __syncthreads();
        for (int kk = 0; kk < 64; kk += 32) {
            s16x8 af[2], bf[2];
            af[0] = *(const s16x8*)(&As[wr * 32 + lrow][kk + kq * 8]);
            af[1] = *(const s16x8*)(&As[wr * 32 + 16 + lrow][kk + kq * 8]);
            bf[0] = *(const s16x8*)(&Bs[wc * 32 + lrow][kk + kq * 8]);
            bf[1] = *(const s16x8*)(&Bs[wc * 32 + 16 + lrow][kk + kq * 8]);
            for (int m2 = 0; m2 < 2; ++m2)
                for (int n2 = 0; n2 < 2; ++n2)
                    acc[m2][n2] = __builtin_amdgcn_mfma_f32_16x16x32_bf16(af[m2], bf[n2], acc[m2][n2], 0, 0, 0);
        }
    }
    for (int m2 = 0; m2 < 2; ++m2)
        for (int n2 = 0; n2 < 2; ++n2) {
            int col = n0 + wc * 32 + n2 * 16 + lrow;
            float bvv = bias ? bias[col] : 0.0f;
            for (int j = 0; j < 4; ++j) {
                int row = m0 + wr * 32 + m2 * 16 + kq * 4 + j;
                float v = acc[m2][n2][j] + bvv;
                if (OUT_BF16) ((short*)Cp)[(size_t)row * N + col] = (short)f2b(v);
                else          ((float*)Cp)[(size_t)row * N + col] = v;
            }
        }
}

__global__ __launch_bounds__(256)
void init_state(const float* __restrict__ e_h, const float* __restrict__ e_c,
                float* __restrict__ c, short* __restrict__ hcbf,
                short* __restrict__ xcat, const float* __restrict__ E)
{
    int gid = blockIdx.x * 256 + threadIdx.x;
    int b = gid >> 9, d = gid & 511;
    float h0 = e_h[gid], c0 = e_c[gid];
    c[gid] = c0;
    hcbf[gid] = (short)f2b(h0 + c0);
    xcat[(size_t)b * 1536 + 1024 + d] = (short)f2b(h0);
    xcat[(size_t)b * 1536 + d] = (short)f2b(E[d]);
}

__global__ __launch_bounds__(256)
void transpose_cast(const float* __restrict__ in, short* __restrict__ out,
                    int K, int N, int ostride, int koff, int gate_perm)
{
    __shared__ float tile[64][65];
    int t = threadIdx.x;
    int n0 = blockIdx.x * 64, k0 = blockIdx.y * 64;
    int cc = t & 63, r4 = t >> 6;
    for (int i = 0; i < 16; ++i) {
        int r = i * 4 + r4;
        tile[r][cc] = in[(size_t)(k0 + r) * N + n0 + cc];
    }
    __syncthreads();
    for (int i = 0; i < 16; ++i) {
        int nr = i * 4 + r4;
        int ng = n0 + nr;
        int np = gate_perm ? ((ng & 511) * 4 + (ng >> 9)) : ng;
        out[(size_t)np * ostride + koff + k0 + cc] = (short)f2b(tile[cc][nr]);
    }
}

__global__ __launch_bounds__(256)
void cast_bf16_v4(const float* __restrict__ in, short* __restrict__ out, int n4)
{
    int i = blockIdx.x * 256 + threadIdx.x;
    int stride = gridDim.x * 256;
    for (; i < n4; i += stride) {
        f32x4 v = ((const f32x4*)in)[i];
        s16x4 o;
        for (int j = 0; j < 4; ++j) o[j] = (short)f2b(v[j]);
        ((s16x4*)out)[i] = o;
    }
}

__global__ __launch_bounds__(256)
void make_bcat(const float* __restrict__ b_ih, const float* __restrict__ b_hh, float* __restrict__ bcat)
{
    int i = blockIdx.x * 256 + threadIdx.x;
    if (i < 2048) {
        int np = (i & 511) * 4 + (i >> 9);
        bcat[np] = b_ih[i] + b_hh[i];
    }
}

extern "C" void kernel_launch(void* const* d_in, const int* in_sizes, int n_in,
                              void* d_out, int out_size, void* d_ws, size_t ws_size,
                              hipStream_t stream)
{
    const float* e_all  = (const float*)d_in[0];
    const float* e_h    = (const float*)d_in[1];
    const float* e_c    = (const float*)d_in[2];
    const int*   target = (const int*)d_in[3];
    const float* E      = (const float*)d_in[4];
    const float* Wa     = (const float*)d_in[5];
    const float* ba     = (const float*)d_in[6];
    const float* Ua     = (const float*)d_in[7];
    const float* bu     = (const float*)d_in[8];
    const float* Va     = (const float*)d_in[9];
    const float* bv     = (const float*)d_in[10];
    const float* W_ih   = (const float*)d_in[11];
    const float* b_ih   = (const float*)d_in[12];
    const float* W_hh   = (const float*)d_in[13];
    const float* b_hh   = (const float*)d_in[14];
    const float* W_out  = (const float*)d_in[15];
    const float* b_out  = (const float*)d_in[16];

    char* ws = (char*)d_ws;
    size_t off = 0;
    auto alloc = [&](size_t bytes) { void* p = ws + off; off += (bytes + 255) & ~255ull; return p; };
    short* ealb  = (short*)alloc((size_t)B_ * S_ * D_ * 2);
    short* kpb   = (short*)alloc((size_t)B_ * S_ * D_ * 2);
    short* WaT   = (short*)alloc((size_t)D_ * D_ * 2);
    short* UaT   = (short*)alloc((size_t)D_ * D_ * 2);
    short* WcatT = (short*)alloc((size_t)2048 * 1536 * 2);
    short* WoutT = (short*)alloc((size_t)V_ * D_ * 2);
    float* bcat  = (float*)alloc(2048 * 4);
    float* qb    = (float*)alloc((size_t)B_ * D_ * 4);
    short* xcat0 = (short*)alloc((size_t)B_ * 1536 * 2);
    short* xcat1 = (short*)alloc((size_t)B_ * 1536 * 2);
    short* hcbf  = (short*)alloc((size_t)B_ * D_ * 2);
    short* h2bf  = (short*)alloc((size_t)B_ * D_ * 2);
    float* cst   = (float*)alloc((size_t)B_ * D_ * 4);
    if (off > ws_size) return;

    float* out_logits = (float*)d_out;                        // [B,T,V]
    float* out_attn   = (float*)d_out + (size_t)B_ * T_ * V_; // [B,T,S]

    // ---- precompute ----
    cast_bf16_v4<<<4096, 256, 0, stream>>>(e_all, ealb, B_ * S_ * D_ / 4);
    transpose_cast<<<dim3(8, 8),   256, 0, stream>>>(Wa,    WaT,   512,  512,  512, 0, 0);
    transpose_cast<<<dim3(8, 8),   256, 0, stream>>>(Ua,    UaT,   512,  512,  512, 0, 0);
    transpose_cast<<<dim3(32, 16), 256, 0, stream>>>(W_ih,  WcatT, 1024, 2048, 1536, 0, 1);
    transpose_cast<<<dim3(32, 8),  256, 0, stream>>>(W_hh,  WcatT, 512,  2048, 1536, 1024, 1);
    transpose_cast<<<dim3(2, 8),   256, 0, stream>>>(W_out, WoutT, 512,  128,  512, 0, 0);
    make_bcat<<<8, 256, 0, stream>>>(b_ih, b_hh, bcat);
    gemm64<true><<<dim3(8, 1024), 256, 0, stream>>>(ealb, UaT, bu, kpb, B_ * S_, 512, 512);
    init_state<<<1024, 256, 0, stream>>>(e_h, e_c, cst, hcbf, xcat0, E);
    gemm64<false><<<dim3(8, 8), 256, 0, stream>>>(hcbf, WaT, ba, qb, B_, 512, 512);

    // ---- persistent cooperative decode ----
    P pp;
    pp.target = target; pp.E = E; pp.Va = Va; pp.bv = bv; pp.ba = ba; pp.bout = b_out;
    pp.ealb = ealb; pp.kpb = kpb; pp.WaT = WaT; pp.WcatT = WcatT; pp.WoutT = WoutT;
    pp.bcat = bcat; pp.qb = qb; pp.xcat0 = xcat0; pp.xcat1 = xcat1;
    pp.hcbf = hcbf; pp.h2bf = h2bf; pp.cst = cst;
    pp.out_logits = out_logits; pp.out_attn = out_attn;

    void* args[] = { (void*)&pp };
    hipError_t ce = hipLaunchCooperativeKernel((const void*)decode_all,
                                               dim3(512), dim3(256), args, 0u, stream);
    if (ce != hipSuccess) {
        // fallback: per-step kernels (same phases, same buffers)
        for (int t = 0; t < T_; ++t) {
            attn_k<<<512, 256, 0, stream>>>(pp, t);
            gate_k<<<256, 256, 0, stream>>>(pp, t);
            qout_k<<<136, 256, 0, stream>>>(pp, t);
        }
    }
    (void)n_in; (void)in_sizes; (void)out_size;
}

// Round 4
// 7295.632 us; speedup vs baseline: 4.2467x; 4.2467x over previous
//
#include <hip/hip_runtime.h>

#define B_ 512
#define S_ 128
#define T_ 128
#define D_ 512
#define V_ 128
#define LDW 72   // 144B row stride -> 2-way LDS bank aliasing on ds_read_b128 (free)

typedef __attribute__((ext_vector_type(8))) short s16x8;
typedef __attribute__((ext_vector_type(4))) short s16x4;
typedef __attribute__((ext_vector_type(4))) float f32x4;

__device__ __forceinline__ float b2f(unsigned short h) {
    union { unsigned int u; float f; } x; x.u = ((unsigned int)h) << 16; return x.f;
}
__device__ __forceinline__ unsigned short f2b(float f) {
    union { float f; unsigned int u; } x; x.f = f;
    unsigned int u = x.u; u += 0x7FFFu + ((u >> 16) & 1u);
    return (unsigned short)(u >> 16);
}
#if __has_builtin(__builtin_amdgcn_rcpf)
__device__ __forceinline__ float rcp_f(float x) { return __builtin_amdgcn_rcpf(x); }
#else
__device__ __forceinline__ float rcp_f(float x) { return 1.0f / x; }
#endif
__device__ __forceinline__ float sigm(float x) { return rcp_f(1.0f + __expf(-x)); }
__device__ __forceinline__ float tanh_fast(float x) {
    float e = __expf(2.0f * fabsf(x));          // e^{2|x|}; inf -> rcp=0 -> 1.0
    float r = 1.0f - 2.0f * rcp_f(e + 1.0f);
    return copysignf(r, x);
}

struct P {
    const int* target;
    const float* E; const float* Va; const float* bv; const float* ba; const float* bout;
    const short* ealb; const short* kpb;
    const short* WaT; const short* WehT; const short* WctxT; const short* WoutT;
    const float* bcat;
    float* qb; short* xeh; short* ctxb; float* gp;
    short* hcbf; short* h2bf; float* cst;
    float* out_logits; float* out_attn;
};

struct AttnS { float sc[S_]; float wbuf[S_]; float red[2]; float cpart[4][D_]; };
struct GateS { short As[64][LDW]; short Bs[64][LDW]; float gt[64][68]; };
struct OutS  { short As[64][LDW]; short Bs[128][LDW]; };
union SharedU { AttnS a; GateS g; OutS o; };

// ---------------- attention: scores + softmax + ctx (block b = batch row) ----------------
__device__ __forceinline__ void attn_phase(const P& p, AttnS& sh, int b, int step)
{
    const int t = threadIdx.x, lane = t & 63, wave = t >> 6;
    const int d0 = lane * 8;
    float qr[8], var[8];
    const float* qrow = p.qb + (size_t)b * D_ + d0;
    #pragma unroll
    for (int j = 0; j < 8; ++j) { qr[j] = qrow[j]; var[j] = p.Va[d0 + j]; }
    const float bvv = p.bv[0];
    #pragma unroll 4
    for (int i = 0; i < 32; ++i) {
        int s = wave * 32 + i;
        s16x8 kv = *(const s16x8*)(p.kpb + ((size_t)b * S_ + s) * D_ + d0);
        float acc = 0.f;
        #pragma unroll
        for (int j = 0; j < 8; ++j)
            acc += tanh_fast(qr[j] + b2f((unsigned short)kv[j])) * var[j];
        #pragma unroll
        for (int o = 32; o >= 1; o >>= 1) acc += __shfl_xor(acc, o);
        if (lane == 0) sh.sc[s] = acc + bvv;
    }
    __syncthreads();
    if (wave == 0) {
        float v0 = sh.sc[lane], v1 = sh.sc[lane + 64];
        float m = fmaxf(v0, v1);
        #pragma unroll
        for (int o = 32; o >= 1; o >>= 1) m = fmaxf(m, __shfl_xor(m, o));
        float su = __expf(v0 - m) + __expf(v1 - m);
        #pragma unroll
        for (int o = 32; o >= 1; o >>= 1) su += __shfl_xor(su, o);
        if (lane == 0) { sh.red[0] = m; sh.red[1] = su; }
    }
    __syncthreads();
    {
        float m = sh.red[0], inv = rcp_f(sh.red[1]);
        if (t < S_) {
            float w = __expf(sh.sc[t] - m) * inv;
            sh.wbuf[t] = w;
            p.out_attn[((size_t)b * T_ + step) * S_ + t] = w;
        }
    }
    __syncthreads();
    {
        f32x4 aA = {0.f,0.f,0.f,0.f}, aB = {0.f,0.f,0.f,0.f};
        const short* eb = p.ealb + (size_t)b * S_ * D_ + d0;
        #pragma unroll 4
        for (int i = 0; i < 32; ++i) {
            int s = wave * 32 + i;
            float wv = sh.wbuf[s];
            s16x8 ev = *(const s16x8*)(eb + (size_t)s * D_);
            #pragma unroll
            for (int j = 0; j < 4; ++j) aA[j] += wv * b2f((unsigned short)ev[j]);
            #pragma unroll
            for (int j = 0; j < 4; ++j) aB[j] += wv * b2f((unsigned short)ev[4 + j]);
        }
        *(f32x4*)&sh.cpart[wave][d0]     = aA;
        *(f32x4*)&sh.cpart[wave][d0 + 4] = aB;
    }
    __syncthreads();
    {
        int dd = t * 2;
        float v0 = sh.cpart[0][dd]   + sh.cpart[1][dd]   + sh.cpart[2][dd]   + sh.cpart[3][dd];
        float v1 = sh.cpart[0][dd+1] + sh.cpart[1][dd+1] + sh.cpart[2][dd+1] + sh.cpart[3][dd+1];
        short2 o2; o2.x = (short)f2b(v0); o2.y = (short)f2b(v1);
        *(short2*)(p.ctxb + (size_t)b * D_ + dd) = o2;
    }
}

// ---------------- partial gate GEMM: Gp = [emb,h] @ W_eh^T + bcat   (K=1024, gate-interleaved N) ----
__device__ __forceinline__ void pgate_phase(const P& p, GateS& sh, int bid2)
{
    const int t = threadIdx.x, lane = t & 63, wave = t >> 6;
    const int wr = wave >> 1, wc = wave & 1;
    const int lrow = lane & 15, kq = lane >> 4;
    const int srow = t >> 3, sseg = t & 7;
    const int m0 = (bid2 >> 5) * 64, n0 = (bid2 & 31) * 64;
    const int K = 1024;
    f32x4 acc[2][2] = {};
    for (int k0 = 0; k0 < K; k0 += 64) {
        s16x8 va0 = *(const s16x8*)(p.xeh + (size_t)(m0 + srow) * K + k0 + sseg * 8);
        s16x8 va1 = *(const s16x8*)(p.xeh + (size_t)(m0 + srow + 32) * K + k0 + sseg * 8);
        s16x8 vb0 = *(const s16x8*)(p.WehT + (size_t)(n0 + srow) * K + k0 + sseg * 8);
        s16x8 vb1 = *(const s16x8*)(p.WehT + (size_t)(n0 + srow + 32) * K + k0 + sseg * 8);
        __syncthreads();
        *(s16x8*)(&sh.As[srow][sseg * 8]) = va0;
        *(s16x8*)(&sh.As[srow + 32][sseg * 8]) = va1;
        *(s16x8*)(&sh.Bs[srow][sseg * 8]) = vb0;
        *(s16x8*)(&sh.Bs[srow + 32][sseg * 8]) = vb1;
        __syncthreads();
        #pragma unroll
        for (int kk = 0; kk < 64; kk += 32) {
            s16x8 af0 = *(const s16x8*)(&sh.As[wr * 32 + lrow][kk + kq * 8]);
            s16x8 af1 = *(const s16x8*)(&sh.As[wr * 32 + 16 + lrow][kk + kq * 8]);
            s16x8 bf0 = *(const s16x8*)(&sh.Bs[wc * 32 + lrow][kk + kq * 8]);
            s16x8 bf1 = *(const s16x8*)(&sh.Bs[wc * 32 + 16 + lrow][kk + kq * 8]);
            acc[0][0] = __builtin_amdgcn_mfma_f32_16x16x32_bf16(af0, bf0, acc[0][0], 0, 0, 0);
            acc[0][1] = __builtin_amdgcn_mfma_f32_16x16x32_bf16(af0, bf1, acc[0][1], 0, 0, 0);
            acc[1][0] = __builtin_amdgcn_mfma_f32_16x16x32_bf16(af1, bf0, acc[1][0], 0, 0, 0);
            acc[1][1] = __builtin_amdgcn_mfma_f32_16x16x32_bf16(af1, bf1, acc[1][1], 0, 0, 0);
        }
    }
    #pragma unroll
    for (int m2 = 0; m2 < 2; ++m2)
        #pragma unroll
        for (int n2 = 0; n2 < 2; ++n2) {
            int cl = wc * 32 + n2 * 16 + lrow;
            float bvv = p.bcat[n0 + cl];
            #pragma unroll
            for (int j = 0; j < 4; ++j) {
                int rl = wr * 32 + m2 * 16 + kq * 4 + j;
                p.gp[(size_t)(m0 + rl) * 2048 + n0 + cl] = acc[m2][n2][j] + bvv;
            }
        }
}

// ---------------- final gate GEMM (K=512, ctx) + Gp + fused LSTM ----------------
__device__ __forceinline__ void fgate_phase(const P& p, GateS& sh, int bid, int step)
{
    const int t = threadIdx.x, lane = t & 63, wave = t >> 6;
    const int wr = wave >> 1, wc = wave & 1;
    const int lrow = lane & 15, kq = lane >> 4;
    const int srow = t >> 3, sseg = t & 7;
    const int m0 = (bid >> 5) * 64, n0 = (bid & 31) * 64;
    f32x4 acc[2][2] = {};
    for (int k0 = 0; k0 < 512; k0 += 64) {
        s16x8 va0 = *(const s16x8*)(p.ctxb + (size_t)(m0 + srow) * 512 + k0 + sseg * 8);
        s16x8 va1 = *(const s16x8*)(p.ctxb + (size_t)(m0 + srow + 32) * 512 + k0 + sseg * 8);
        s16x8 vb0 = *(const s16x8*)(p.WctxT + (size_t)(n0 + srow) * 512 + k0 + sseg * 8);
        s16x8 vb1 = *(const s16x8*)(p.WctxT + (size_t)(n0 + srow + 32) * 512 + k0 + sseg * 8);
        __syncthreads();
        *(s16x8*)(&sh.As[srow][sseg * 8]) = va0;
        *(s16x8*)(&sh.As[srow + 32][sseg * 8]) = va1;
        *(s16x8*)(&sh.Bs[srow][sseg * 8]) = vb0;
        *(s16x8*)(&sh.Bs[srow + 32][sseg * 8]) = vb1;
        __syncthreads();
        #pragma unroll
        for (int kk = 0; kk < 64; kk += 32) {
            s16x8 af0 = *(const s16x8*)(&sh.As[wr * 32 + lrow][kk + kq * 8]);
            s16x8 af1 = *(const s16x8*)(&sh.As[wr * 32 + 16 + lrow][kk + kq * 8]);
            s16x8 bf0 = *(const s16x8*)(&sh.Bs[wc * 32 + lrow][kk + kq * 8]);
            s16x8 bf1 = *(const s16x8*)(&sh.Bs[wc * 32 + 16 + lrow][kk + kq * 8]);
            acc[0][0] = __builtin_amdgcn_mfma_f32_16x16x32_bf16(af0, bf0, acc[0][0], 0, 0, 0);
            acc[0][1] = __builtin_amdgcn_mfma_f32_16x16x32_bf16(af0, bf1, acc[0][1], 0, 0, 0);
            acc[1][0] = __builtin_amdgcn_mfma_f32_16x16x32_bf16(af1, bf0, acc[1][0], 0, 0, 0);
            acc[1][1] = __builtin_amdgcn_mfma_f32_16x16x32_bf16(af1, bf1, acc[1][1], 0, 0, 0);
        }
    }
    #pragma unroll
    for (int m2 = 0; m2 < 2; ++m2)
        #pragma unroll
        for (int n2 = 0; n2 < 2; ++n2) {
            int cl = wc * 32 + n2 * 16 + lrow;
            #pragma unroll
            for (int j = 0; j < 4; ++j) {
                int rl = wr * 32 + m2 * 16 + kq * 4 + j;
                sh.gt[rl][cl] = acc[m2][n2][j] + p.gp[(size_t)(m0 + rl) * 2048 + n0 + cl];
            }
        }
    __syncthreads();
    const int rl4 = t >> 4, dl = t & 15;
    #pragma unroll
    for (int pass = 0; pass < 4; ++pass) {
        int row = pass * 16 + rl4;
        int b = m0 + row;
        int d = (n0 >> 2) + dl;
        float gi = sh.gt[row][dl * 4 + 0];
        float gf = sh.gt[row][dl * 4 + 1];
        float gg = sh.gt[row][dl * 4 + 2];
        float go = sh.gt[row][dl * 4 + 3];
        float cv = p.cst[(size_t)b * D_ + d];
        float c2 = sigm(gf) * cv + sigm(gi) * tanh_fast(gg);
        float h2 = sigm(go) * tanh_fast(c2);
        p.cst[(size_t)b * D_ + d] = c2;
        p.hcbf[(size_t)b * D_ + d] = (short)f2b(h2 + c2);
        p.h2bf[(size_t)b * D_ + d] = (short)f2b(h2);
        p.xeh[(size_t)b * 1024 + 512 + d] = (short)f2b(h2);
        int tok = p.target[b * T_ + step];
        p.xeh[(size_t)b * 1024 + d] = (short)f2b(p.E[(size_t)tok * D_ + d]);
    }
}

// ---------------- q GEMM 64x32 tiles (128 blocks) ----------------
__device__ __forceinline__ void q_phase(const P& p, OutS& sh, int bid)
{
    const int t = threadIdx.x, lane = t & 63, wave = t >> 6;
    const int lrow = lane & 15, kq = lane >> 4;
    const int srow = t >> 3, sseg = t & 7;
    const int m0 = (bid >> 4) * 64, n0 = (bid & 15) * 32;
    f32x4 acc0 = {}, acc1 = {};
    for (int k0 = 0; k0 < 512; k0 += 64) {
        s16x8 va0 = *(const s16x8*)(p.hcbf + (size_t)(m0 + srow) * 512 + k0 + sseg * 8);
        s16x8 va1 = *(const s16x8*)(p.hcbf + (size_t)(m0 + srow + 32) * 512 + k0 + sseg * 8);
        s16x8 vb0 = *(const s16x8*)(p.WaT + (size_t)(n0 + srow) * 512 + k0 + sseg * 8);
        __syncthreads();
        *(s16x8*)(&sh.As[srow][sseg * 8]) = va0;
        *(s16x8*)(&sh.As[srow + 32][sseg * 8]) = va1;
        if (srow < 32) *(s16x8*)(&sh.Bs[srow][sseg * 8]) = vb0;
        __syncthreads();
        #pragma unroll
        for (int kk = 0; kk < 64; kk += 32) {
            s16x8 af  = *(const s16x8*)(&sh.As[wave * 16 + lrow][kk + kq * 8]);
            s16x8 bf0 = *(const s16x8*)(&sh.Bs[lrow][kk + kq * 8]);
            s16x8 bf1 = *(const s16x8*)(&sh.Bs[16 + lrow][kk + kq * 8]);
            acc0 = __builtin_amdgcn_mfma_f32_16x16x32_bf16(af, bf0, acc0, 0, 0, 0);
            acc1 = __builtin_amdgcn_mfma_f32_16x16x32_bf16(af, bf1, acc1, 0, 0, 0);
        }
    }
    #pragma unroll
    for (int n2 = 0; n2 < 2; ++n2) {
        int col = n0 + n2 * 16 + lrow;
        float bvv = p.ba[col];
        f32x4 av = n2 ? acc1 : acc0;
        #pragma unroll
        for (int j = 0; j < 4; ++j) {
            int row = m0 + wave * 16 + kq * 4 + j;
            p.qb[(size_t)row * 512 + col] = av[j] + bvv;
        }
    }
}

// ---------------- out GEMM (M=512,N=128,K=512) + fused log_softmax (8 blocks) ----------------
__device__ __forceinline__ void out_phase(const P& p, OutS& sh, int obid, int step)
{
    const int t = threadIdx.x, lane = t & 63, wave = t >> 6;
    const int lrow = lane & 15, kq = lane >> 4;
    const int srow = t >> 3, sseg = t & 7;
    const int m0 = obid * 64;
    f32x4 acc[8] = {};
    for (int k0 = 0; k0 < 512; k0 += 64) {
        s16x8 va0 = *(const s16x8*)(p.h2bf + (size_t)(m0 + srow) * 512 + k0 + sseg * 8);
        s16x8 va1 = *(const s16x8*)(p.h2bf + (size_t)(m0 + srow + 32) * 512 + k0 + sseg * 8);
        s16x8 vb[4];
        #pragma unroll
        for (int p4 = 0; p4 < 4; ++p4)
            vb[p4] = *(const s16x8*)(p.WoutT + (size_t)(srow + p4 * 32) * 512 + k0 + sseg * 8);
        __syncthreads();
        *(s16x8*)(&sh.As[srow][sseg * 8]) = va0;
        *(s16x8*)(&sh.As[srow + 32][sseg * 8]) = va1;
        #pragma unroll
        for (int p4 = 0; p4 < 4; ++p4) *(s16x8*)(&sh.Bs[srow + p4 * 32][sseg * 8]) = vb[p4];
        __syncthreads();
        #pragma unroll
        for (int kk = 0; kk < 64; kk += 32) {
            s16x8 a = *(const s16x8*)(&sh.As[wave * 16 + lrow][kk + kq * 8]);
            #pragma unroll
            for (int f = 0; f < 8; ++f) {
                s16x8 b = *(const s16x8*)(&sh.Bs[f * 16 + lrow][kk + kq * 8]);
                acc[f] = __builtin_amdgcn_mfma_f32_16x16x32_bf16(a, b, acc[f], 0, 0, 0);
            }
        }
    }
    float colb[8];
    #pragma unroll
    for (int f = 0; f < 8; ++f) colb[f] = p.bout[f * 16 + lrow];
    #pragma unroll
    for (int j = 0; j < 4; ++j) {
        float v[8]; float mx = -1e30f;
        #pragma unroll
        for (int f = 0; f < 8; ++f) { v[f] = acc[f][j] + colb[f]; mx = fmaxf(mx, v[f]); }
        #pragma unroll
        for (int o = 1; o < 16; o <<= 1) mx = fmaxf(mx, __shfl_xor(mx, o));
        float sum = 0.f;
        #pragma unroll
        for (int f = 0; f < 8; ++f) sum += __expf(v[f] - mx);
        #pragma unroll
        for (int o = 1; o < 16; o <<= 1) sum += __shfl_xor(sum, o);
        float lse = mx + __logf(sum);
        int row = m0 + wave * 16 + kq * 4 + j;
        float* orow = p.out_logits + ((size_t)row * T_ + step) * V_;
        #pragma unroll
        for (int f = 0; f < 8; ++f) orow[f * 16 + lrow] = v[f] - lse;
    }
}

// ---------------- per-step dispatches ----------------
__global__ __launch_bounds__(256, 2) void kA(P p, int step) {
    __shared__ SharedU sh;
    const int bid = blockIdx.x;
    if (bid < 512)       attn_phase(p, sh.a, bid, step);
    else if (bid < 768)  pgate_phase(p, sh.g, bid - 512);
    else if (step > 0)   out_phase(p, sh.o, bid - 768, step - 1);
}
__global__ __launch_bounds__(256, 2) void kB(P p, int step) {
    __shared__ SharedU sh;
    fgate_phase(p, sh.g, blockIdx.x, step);
}
__global__ __launch_bounds__(256, 2) void kC(P p) {
    __shared__ SharedU sh;
    q_phase(p, sh.o, blockIdx.x);
}
__global__ __launch_bounds__(256, 2) void kOutLast(P p, int step) {
    __shared__ SharedU sh;
    out_phase(p, sh.o, blockIdx.x, step);
}

// ---------------- precompute kernels ----------------
template<bool OUT_BF16>
__global__ __launch_bounds__(256)
void gemm64(const short* __restrict__ A, const short* __restrict__ Bt,
            const float* __restrict__ bias, void* __restrict__ Cp,
            int M, int N, int K)
{
    __shared__ __align__(16) short As[64][LDW];
    __shared__ __align__(16) short Bs[64][LDW];
    const int t = threadIdx.x;
    const int lane = t & 63, wave = t >> 6;
    const int wr = wave >> 1, wc = wave & 1;
    const int lrow = lane & 15, kq = lane >> 4;
    const int m0 = blockIdx.y * 64, n0 = blockIdx.x * 64;
    const int srow = t >> 3, sseg = t & 7;
    f32x4 acc[2][2] = {};
    for (int k0 = 0; k0 < K; k0 += 64) {
        s16x8 va0 = *(const s16x8*)(A + (size_t)(m0 + srow) * K + k0 + sseg * 8);
        s16x8 va1 = *(const s16x8*)(A + (size_t)(m0 + srow + 32) * K + k0 + sseg * 8);
        s16x8 vb0 = *(const s16x8*)(Bt + (size_t)(n0 + srow) * K + k0 + sseg * 8);
        s16x8 vb1 = *(const s16x8*)(Bt + (size_t)(n0 + srow + 32) * K + k0 + sseg * 8);
        __syncthreads();
        *(s16x8*)(&As[srow][sseg * 8]) = va0;
        *(s16x8*)(&As[srow + 32][sseg * 8]) = va1;
        *(s16x8*)(&Bs[srow][sseg * 8]) = vb0;
        *(s16x8*)(&Bs[srow + 32][sseg * 8]) = vb1;
        __syncthreads();
        for (int kk = 0; kk < 64; kk += 32) {
            s16x8 af[2], bf[2];
            af[0] = *(const s16x8*)(&As[wr * 32 + lrow][kk + kq * 8]);
            af[1] = *(const s16x8*)(&As[wr * 32 + 16 + lrow][kk + kq * 8]);
            bf[0] = *(const s16x8*)(&Bs[wc * 32 + lrow][kk + kq * 8]);
            bf[1] = *(const s16x8*)(&Bs[wc * 32 + 16 + lrow][kk + kq * 8]);
            for (int m2 = 0; m2 < 2; ++m2)
                for (int n2 = 0; n2 < 2; ++n2)
                    acc[m2][n2] = __builtin_amdgcn_mfma_f32_16x16x32_bf16(af[m2], bf[n2], acc[m2][n2], 0, 0, 0);
        }
    }
    for (int m2 = 0; m2 < 2; ++m2)
        for (int n2 = 0; n2 < 2; ++n2) {
            int col = n0 + wc * 32 + n2 * 16 + lrow;
            float bvv = bias ? bias[col] : 0.0f;
            for (int j = 0; j < 4; ++j) {
                int row = m0 + wr * 32 + m2 * 16 + kq * 4 + j;
                float v = acc[m2][n2][j] + bvv;
                if (OUT_BF16) ((short*)Cp)[(size_t)row * N + col] = (short)f2b(v);
                else          ((float*)Cp)[(size_t)row * N + col] = v;
            }
        }
}

__global__ __launch_bounds__(256)
void init_state(const float* __restrict__ e_h, const float* __restrict__ e_c,
                float* __restrict__ c, short* __restrict__ hcbf,
                short* __restrict__ xeh, const float* __restrict__ E)
{
    int gid = blockIdx.x * 256 + threadIdx.x;
    int b = gid >> 9, d = gid & 511;
    float h0 = e_h[gid], c0 = e_c[gid];
    c[gid] = c0;
    hcbf[gid] = (short)f2b(h0 + c0);
    xeh[(size_t)b * 1024 + 512 + d] = (short)f2b(h0);
    xeh[(size_t)b * 1024 + d] = (short)f2b(E[d]);   // token 0 (SOS)
}

__global__ __launch_bounds__(256)
void transpose_cast(const float* __restrict__ in, short* __restrict__ out,
                    int N, int ostride, int koff, int gate_perm)
{
    __shared__ float tile[64][65];
    int t = threadIdx.x;
    int n0 = blockIdx.x * 64, k0 = blockIdx.y * 64;
    int cc = t & 63, r4 = t >> 6;
    for (int i = 0; i < 16; ++i) {
        int r = i * 4 + r4;
        tile[r][cc] = in[(size_t)(k0 + r) * N + n0 + cc];
    }
    __syncthreads();
    for (int i = 0; i < 16; ++i) {
        int nr = i * 4 + r4;
        int ng = n0 + nr;
        int np = gate_perm ? ((ng & 511) * 4 + (ng >> 9)) : ng;
        out[(size_t)np * ostride + koff + k0 + cc] = (short)f2b(tile[cc][nr]);
    }
}

__global__ __launch_bounds__(256)
void cast_bf16_v4(const float* __restrict__ in, short* __restrict__ out, int n4)
{
    int i = blockIdx.x * 256 + threadIdx.x;
    int stride = gridDim.x * 256;
    for (; i < n4; i += stride) {
        f32x4 v = ((const f32x4*)in)[i];
        s16x4 o;
        for (int j = 0; j < 4; ++j) o[j] = (short)f2b(v[j]);
        ((s16x4*)out)[i] = o;
    }
}

__global__ __launch_bounds__(256)
void make_bcat(const float* __restrict__ b_ih, const float* __restrict__ b_hh, float* __restrict__ bcat)
{
    int i = blockIdx.x * 256 + threadIdx.x;
    if (i < 2048) {
        int np = (i & 511) * 4 + (i >> 9);
        bcat[np] = b_ih[i] + b_hh[i];
    }
}

extern "C" void kernel_launch(void* const* d_in, const int* in_sizes, int n_in,
                              void* d_out, int out_size, void* d_ws, size_t ws_size,
                              hipStream_t stream)
{
    const float* e_all  = (const float*)d_in[0];
    const float* e_h    = (const float*)d_in[1];
    const float* e_c    = (const float*)d_in[2];
    const int*   target = (const int*)d_in[3];
    const float* E      = (const float*)d_in[4];
    const float* Wa     = (const float*)d_in[5];
    const float* ba     = (const float*)d_in[6];
    const float* Ua     = (const float*)d_in[7];
    const float* bu     = (const float*)d_in[8];
    const float* Va     = (const float*)d_in[9];
    const float* bv     = (const float*)d_in[10];
    const float* W_ih   = (const float*)d_in[11];
    const float* b_ih   = (const float*)d_in[12];
    const float* W_hh   = (const float*)d_in[13];
    const float* b_hh   = (const float*)d_in[14];
    const float* W_out  = (const float*)d_in[15];
    const float* b_out  = (const float*)d_in[16];

    char* ws = (char*)d_ws;
    size_t off = 0;
    auto alloc = [&](size_t bytes) { void* p = ws + off; off += (bytes + 255) & ~255ull; return p; };
    short* ealb  = (short*)alloc((size_t)B_ * S_ * D_ * 2);
    short* kpb   = (short*)alloc((size_t)B_ * S_ * D_ * 2);
    short* WaT   = (short*)alloc((size_t)D_ * D_ * 2);
    short* UaT   = (short*)alloc((size_t)D_ * D_ * 2);
    short* WehT  = (short*)alloc((size_t)2048 * 1024 * 2);
    short* WctxT = (short*)alloc((size_t)2048 * 512 * 2);
    short* WoutT = (short*)alloc((size_t)V_ * D_ * 2);
    float* bcat  = (float*)alloc(2048 * 4);
    float* qb    = (float*)alloc((size_t)B_ * D_ * 4);
    short* xeh   = (short*)alloc((size_t)B_ * 1024 * 2);
    short* ctxb  = (short*)alloc((size_t)B_ * D_ * 2);
    float* gp    = (float*)alloc((size_t)B_ * 2048 * 4);
    short* hcbf  = (short*)alloc((size_t)B_ * D_ * 2);
    short* h2bf  = (short*)alloc((size_t)B_ * D_ * 2);
    float* cst   = (float*)alloc((size_t)B_ * D_ * 4);
    if (off > ws_size) return;

    float* out_logits = (float*)d_out;                        // [B,T,V]
    float* out_attn   = (float*)d_out + (size_t)B_ * T_ * V_; // [B,T,S]

    // ---- precompute ----
    cast_bf16_v4<<<4096, 256, 0, stream>>>(e_all, ealb, B_ * S_ * D_ / 4);
    transpose_cast<<<dim3(8, 8),  256, 0, stream>>>(Wa,  WaT,  512,  512, 0, 0);
    transpose_cast<<<dim3(8, 8),  256, 0, stream>>>(Ua,  UaT,  512,  512, 0, 0);
    transpose_cast<<<dim3(32, 8), 256, 0, stream>>>(W_ih,                 WehT,  2048, 1024, 0,   1);
    transpose_cast<<<dim3(32, 8), 256, 0, stream>>>(W_ih + 512 * 2048,    WctxT, 2048, 512,  0,   1);
    transpose_cast<<<dim3(32, 8), 256, 0, stream>>>(W_hh,                 WehT,  2048, 1024, 512, 1);
    transpose_cast<<<dim3(2, 8),  256, 0, stream>>>(W_out, WoutT, 128, 512, 0, 0);
    make_bcat<<<8, 256, 0, stream>>>(b_ih, b_hh, bcat);
    gemm64<true><<<dim3(8, 1024), 256, 0, stream>>>(ealb, UaT, bu, kpb, B_ * S_, 512, 512);
    init_state<<<1024, 256, 0, stream>>>(e_h, e_c, cst, hcbf, xeh, E);
    gemm64<false><<<dim3(8, 8), 256, 0, stream>>>(hcbf, WaT, ba, qb, B_, 512, 512);

    P pp;
    pp.target = target; pp.E = E; pp.Va = Va; pp.bv = bv; pp.ba = ba; pp.bout = b_out;
    pp.ealb = ealb; pp.kpb = kpb; pp.WaT = WaT; pp.WehT = WehT; pp.WctxT = WctxT; pp.WoutT = WoutT;
    pp.bcat = bcat; pp.qb = qb; pp.xeh = xeh; pp.ctxb = ctxb; pp.gp = gp;
    pp.hcbf = hcbf; pp.h2bf = h2bf; pp.cst = cst;
    pp.out_logits = out_logits; pp.out_attn = out_attn;

    // ---- sequential decode: A(attn ∥ partial-gate ∥ out_{t-1}) -> B(final gate+LSTM) -> C(q_{t+1})
    for (int t = 0; t < T_; ++t) {
        kA<<<776, 256, 0, stream>>>(pp, t);
        kB<<<256, 256, 0, stream>>>(pp, t);
        if (t < T_ - 1) kC<<<128, 256, 0, stream>>>(pp);
    }
    kOutLast<<<8, 256, 0, stream>>>(pp, T_ - 1);
    (void)n_in; (void)in_sizes; (void)out_size;
}